// Round 12
// baseline (180.314 us; speedup 1.0000x reference)
//
#include <hip/hip_runtime.h>
#include <hip/hip_bf16.h>

#define TDEPTH 6
#define NLEAF 64
#define NGATE 63
#define INF 512
#define OUTF 512
#define BATCH 1024
#define SPLITK 16

typedef __attribute__((ext_vector_type(4)))  float f32x4;
typedef __attribute__((ext_vector_type(16))) float f32x16;
typedef __attribute__((ext_vector_type(8)))  __bf16 bf16x8;

__device__ __forceinline__ bf16x8 pack8(f32x4 a, f32x4 b) {
  bf16x8 w;
  w[0] = (__bf16)a[0]; w[1] = (__bf16)a[1];
  w[2] = (__bf16)a[2]; w[3] = (__bf16)a[3];
  w[4] = (__bf16)b[0]; w[5] = (__bf16)b[1];
  w[6] = (__bf16)b[2]; w[7] = (__bf16)b[3];
  return w;
}

// ---------------- kernel 1: leaf probs + fragment-major pwb pack ----------
// blocks [0,256): leaf.
// blocks [256,256+1026): pack pw (+pb as plane 512) into MFMA-fragment order:
//   granule-set S = (nb32*513 + i)*4 + kc   (16 nb32 x 513 planes x 4 kchunks)
//   lane granule (16B, 8 bf16) = pw[o = nb32*32 + (lane&31)][i]
//                                  [l = kc*16 + (lane>>5)*8 + 0..7]
// -> gemm loads B-frags as ONE coalesced dwordx4 per fragment (1KB/wave).
__global__ __launch_bounds__(256) void prep_kernel(
    const float* __restrict__ x, const float* __restrict__ gw,
    const float* __restrict__ gb, const float* __restrict__ pw,
    const float* __restrict__ pb, float* __restrict__ leaf,
    __bf16* __restrict__ pwb) {
  const int tid = threadIdx.x;
  if (blockIdx.x < 256) {
    const int wid = tid >> 6, lane = tid & 63;
    const int b = blockIdx.x * 4 + wid;
    __shared__ float g[4][NLEAF];
    if (lane < NGATE) {
      const float* xr = x + (size_t)b * INF;
      float a0 = 0.f, a1 = 0.f, a2 = 0.f, a3 = 0.f;
      #pragma unroll 4
      for (int i = 0; i < INF; i += 4) {
        a0 += xr[i + 0] * gw[(i + 0) * NGATE + lane];
        a1 += xr[i + 1] * gw[(i + 1) * NGATE + lane];
        a2 += xr[i + 2] * gw[(i + 2) * NGATE + lane];
        a3 += xr[i + 3] * gw[(i + 3) * NGATE + lane];
      }
      float t = (a0 + a1) + (a2 + a3) + gb[lane];
      g[wid][lane] = 1.0f / (1.0f + __expf(-t));
    }
    __syncthreads();
    float p = 1.0f;
    #pragma unroll
    for (int d = 0; d < TDEPTH; d++) {
      int prefix = lane >> (TDEPTH - 1 - d);
      int node = (1 << d) - 1 + (prefix >> 1);
      float gv = g[wid][node];
      p *= (prefix & 1) ? (1.0f - gv) : gv;
    }
    leaf[(size_t)b * NLEAF + lane] = p;
    return;
  }
  // pack: 32 granule-sets per block (8 per wave)
  const int bid2 = blockIdx.x - 256;          // 0..1025
  const int w = tid >> 6, lane = tid & 63;
  const int lo = lane & 31, half = lane >> 5;
  #pragma unroll
  for (int it = 0; it < 8; it++) {
    const unsigned S = (unsigned)bid2 * 32 + w * 8 + it;   // < 32832
    const unsigned i_lin = S >> 2, kc = S & 3;
    const unsigned nb32 = i_lin / 513;
    const unsigned i = i_lin - nb32 * 513;
    const unsigned o = nb32 * 32 + lo;
    const unsigned l = kc * 16 + half * 8;
    const float* src = (i < INF) ? (pw + ((size_t)o * INF + i) * NLEAF + l)
                                 : (pb + (size_t)o * NLEAF + l);
    f32x4 a = *(const f32x4*)src;
    f32x4 b = *(const f32x4*)(src + 4);
    *(bf16x8*)((char*)pwb + (size_t)S * 1024 + (size_t)lane * 16) = pack8(a, b);
  }
}

// ---------------- kernel 2: barrier-free fused GEMM ----------------
// partial[s][b][o] = sum over K-slice of (x[b,i]*leaf[b,l]) * pw[o,i,l]
// 1 wave per block, wave tile 128m x 32o, mfma_f32_32x32x16_bf16.
// B: fragment-major pwb, global->reg double-buffer (coalesced 1KB loads).
// A: resident leaf (128 f32) x x-scalar from wave-private LDS. NO barriers.
__global__ __launch_bounds__(64, 2) void gemm_kernel(
    const __bf16* __restrict__ pwb, const float* __restrict__ x,
    const float* __restrict__ leaf, float* __restrict__ partial) {
  __shared__ __align__(16) float xsm[32][128];   // 16 KB, wave-private

  const int lane = threadIdx.x;
  const int lo = lane & 31, half = lane >> 5;

  // XCD-chunked swizzle: 2048 blocks -> 8 chunks of 256; the 8 mb-sharers of
  // a (nb,s) pwb-slice are adjacent inside one chunk (4MB slice per XCD L2).
  const int L = ((int)blockIdx.x & 7) * 256 + ((int)blockIdx.x >> 3);
  const int mb = L & 7;
  const int rest = L >> 3;
  const int nb32 = rest & 15, s = rest >> 4;
  const int m0 = mb * 128, o0 = nb32 * 32;
  const int cs = s * 32;
  const int count = 32 + (s == SPLITK - 1 ? 1 : 0);  // +1 = bias plane 512

  // stage x[m0..m0+127][cs..cs+31] -> xsm[plane][row] (f32)
  #pragma unroll
  for (int rr = 0; rr < 2; rr++) {
    const int r = lane + rr * 64;
    const float* src = x + (size_t)(m0 + r) * INF + cs;
    #pragma unroll
    for (int c4 = 0; c4 < 8; c4++) {
      f32x4 v = *(const f32x4*)(src + c4 * 4);
      #pragma unroll
      for (int j = 0; j < 4; j++) xsm[c4 * 4 + j][r] = v[j];
    }
  }

  // resident leaf fragments: 4 m-subtiles x 32 f32 (this lane's k-half)
  f32x4 lf[4][4][2];
  #pragma unroll
  for (int ms = 0; ms < 4; ms++) {
    const float* lr = leaf + (size_t)(m0 + ms * 32 + lo) * NLEAF + half * 8;
    #pragma unroll
    for (int t4 = 0; t4 < 4; t4++) {
      lf[ms][t4][0] = *(const f32x4*)(lr + t4 * 16);
      lf[ms][t4][1] = *(const f32x4*)(lr + t4 * 16 + 4);
    }
  }

  f32x16 acc[4];
  #pragma unroll
  for (int ms = 0; ms < 4; ms++) acc[ms] = (f32x16)(0.f);

  // B-fragment base for this (nb32, K-slice); frag t4 of plane t:
  //   + (t*4 + t4)*1024 + lane*16   (one coalesced dwordx4 per frag)
  const char* pwt = (const char*)pwb + ((size_t)(nb32 * 513 + cs) << 12) +
                    (size_t)lane * 16;

  auto loadB = [&](bf16x8(&B)[4], int t) {
    #pragma unroll
    for (int f = 0; f < 4; f++)
      B[f] = *(const bf16x8*)(pwt + ((size_t)t << 12) + (f << 10));
  };

  auto step = [&](const bf16x8(&B)[4], int t) {
    const int tx = t & 31;                  // t==32 -> unused (bias)
    const bool bias = (t >= 32);
    float xv[4];
    #pragma unroll
    for (int ms = 0; ms < 4; ms++)
      xv[ms] = bias ? 1.0f : xsm[tx][ms * 32 + lo];
    #pragma unroll
    for (int t4 = 0; t4 < 4; t4++) {
      #pragma unroll
      for (int ms = 0; ms < 4; ms++) {
        f32x4 pa = lf[ms][t4][0] * xv[ms];
        f32x4 pc = lf[ms][t4][1] * xv[ms];
        bf16x8 a = pack8(pa, pc);
        acc[ms] =
            __builtin_amdgcn_mfma_f32_32x32x16_bf16(a, B[t4], acc[ms], 0, 0, 0);
      }
    }
  };

  // register double-buffered K-loop, no barriers, no LDS for B
  bf16x8 B0[4], B1[4];
  loadB(B0, 0);
  int t = 0;
  while (true) {
    if (t + 1 < count) loadB(B1, t + 1);
    step(B0, t);
    if (++t >= count) break;
    if (t + 1 < count) loadB(B0, t + 1);
    step(B1, t);
    if (++t >= count) break;
  }

  // epilogue: partial[s]; D row = (e&3)+8*(e>>2)+4*half, col = lo
  #pragma unroll
  for (int ms = 0; ms < 4; ms++) {
    float* dst = partial + ((size_t)s * BATCH + m0 + ms * 32) * OUTF + o0;
    #pragma unroll
    for (int e = 0; e < 16; e++) {
      int row = (e & 3) + 8 * (e >> 2) + 4 * half;
      dst[(size_t)row * OUTF + lo] = acc[ms][e];
    }
  }
}

// ---------------- kernel 3: split-K reduce ----------------
__global__ __launch_bounds__(256) void reduce_kernel(
    const float* __restrict__ partial, float* __restrict__ out) {
  size_t e = ((size_t)blockIdx.x * 256 + threadIdx.x) * 4;
  f32x4 sum = (f32x4){0.f, 0.f, 0.f, 0.f};
  #pragma unroll
  for (int s = 0; s < SPLITK; s++)
    sum += *(const f32x4*)(partial + (size_t)s * BATCH * OUTF + e);
  *(f32x4*)(out + e) = sum;
}

extern "C" void kernel_launch(void* const* d_in, const int* in_sizes, int n_in,
                              void* d_out, int out_size, void* d_ws, size_t ws_size,
                              hipStream_t stream) {
  const float* x  = (const float*)d_in[0];
  const float* gw = (const float*)d_in[1];
  const float* gb = (const float*)d_in[2];
  const float* pw = (const float*)d_in[3];
  const float* pb = (const float*)d_in[4];
  float* out = (float*)d_out;

  float*  leaf    = (float*)d_ws;                              // 256 KB
  __bf16* pwb     = (__bf16*)((char*)d_ws + (256 << 10));      // 33.62 MB
  float*  partial = (float*)((char*)d_ws + (256 << 10) + (size_t)16 * 513 * 4096);

  prep_kernel<<<256 + 1026, 256, 0, stream>>>(x, gw, gb, pw, pb, leaf, pwb);
  gemm_kernel<<<2048, 64, 0, stream>>>(pwb, x, leaf, partial);
  reduce_kernel<<<(BATCH * OUTF) / (256 * 4), 256, 0, stream>>>(partial, out);
}

// Round 13
// 76.746 us; speedup vs baseline: 2.3495x; 2.3495x over previous
//
#include <hip/hip_runtime.h>
#include <hip/hip_bf16.h>

#define TDEPTH 6
#define NLEAF 64
#define NGATE 63
#define INF 512
#define OUTF 512
#define BATCH 1024

#define BM 128
#define BN 64
#define SPLITK 16
#define THREADS 128
#define NPL 32        // planes per block (512/SPLITK)

typedef __attribute__((ext_vector_type(4)))  float f32x4;
typedef __attribute__((ext_vector_type(16))) float f32x16;
typedef __attribute__((ext_vector_type(8)))  __bf16 bf16x8;

__device__ __forceinline__ bf16x8 pack8(f32x4 a, f32x4 b) {
  bf16x8 w;
  w[0] = (__bf16)a[0]; w[1] = (__bf16)a[1];
  w[2] = (__bf16)a[2]; w[3] = (__bf16)a[3];
  w[4] = (__bf16)b[0]; w[5] = (__bf16)b[1];
  w[6] = (__bf16)b[2]; w[7] = (__bf16)b[3];
  return w;
}

// ---------------- kernel 1: leaf probs + pwb pack (r10/r11 layout) --------
// blocks [0,256): leaf.  blocks [256,8448): pack pw -> bf16 pwb, tiled per
// (nb, plane): 8KB tile = [32 LDS rows][16 granules]; granule G of row r
// holds pw[o = nb*64 + ((G^(r&15))>>3)*32 + r][i][kg=(G^(r&15))&7]
// -> gemm stages tiles LINEARLY, reads with byte^((lo&15)<<4): conflict-free.
__global__ __launch_bounds__(256) void prep_kernel(
    const float* __restrict__ x, const float* __restrict__ gw,
    const float* __restrict__ gb, const float* __restrict__ pw,
    float* __restrict__ leaf, __bf16* __restrict__ pwb) {
  const int tid = threadIdx.x;
  if (blockIdx.x < 256) {
    const int wid = tid >> 6, lane = tid & 63;
    const int b = blockIdx.x * 4 + wid;
    __shared__ float g[4][NLEAF];
    if (lane < NGATE) {
      const float* xr = x + (size_t)b * INF;
      float a0 = 0.f, a1 = 0.f, a2 = 0.f, a3 = 0.f;
      #pragma unroll 4
      for (int i = 0; i < INF; i += 4) {
        a0 += xr[i + 0] * gw[(i + 0) * NGATE + lane];
        a1 += xr[i + 1] * gw[(i + 1) * NGATE + lane];
        a2 += xr[i + 2] * gw[(i + 2) * NGATE + lane];
        a3 += xr[i + 3] * gw[(i + 3) * NGATE + lane];
      }
      float t = (a0 + a1) + (a2 + a3) + gb[lane];
      g[wid][lane] = 1.0f / (1.0f + __expf(-t));
    }
    __syncthreads();
    float p = 1.0f;
    #pragma unroll
    for (int d = 0; d < TDEPTH; d++) {
      int prefix = lane >> (TDEPTH - 1 - d);
      int node = (1 << d) - 1 + (prefix >> 1);
      float gv = g[wid][node];
      p *= (prefix & 1) ? (1.0f - gv) : gv;
    }
    leaf[(size_t)b * NLEAF + lane] = p;
  } else {
    const unsigned Q = (blockIdx.x - 256) * 256 + tid;   // global granule
    const unsigned tile = Q >> 9;            // nb*512 + i
    const unsigned nb = tile >> 9, i = tile & 511;
    const unsigned q = Q & 511;              // granule within 8KB tile
    const unsigned r = ((q >> 7) << 3) + ((q >> 4) & 7);   // LDS row 0..31
    const unsigned v = (q & 15) ^ (r & 15);
    const unsigned o = nb * 64 + ((v >> 3) << 5) + r;
    const unsigned kg = v & 7;
    const float* src = pw + ((size_t)o * INF + i) * NLEAF + kg * 8;
    f32x4 a = *(const f32x4*)src, b = *(const f32x4*)(src + 4);
    *(bf16x8*)((char*)pwb + (size_t)Q * 16) = pack8(a, b);
  }
}

// async 16B global -> LDS (wave-uniform LDS base; +lane*16 implicit)
__device__ __forceinline__ void gload_lds16(const void* g, void* l) {
  __builtin_amdgcn_global_load_lds(
      (const __attribute__((address_space(1))) void*)g,
      (__attribute__((address_space(3))) void*)l, 16, 0, 0);
}

// ---------------- kernel 2: fused GEMM (phase-split + setprio) ------------
// partial[s][b][o] = sum over K-slice of (x[b,i]*leaf[b,l]) * pw[o,i,l]
// 2 waves/block, wave tile 64m x 64o, mfma_f32_32x32x16_bf16, 3 x 8KB
// B-buffers, counted vmcnt(4). Each plane split into TWO phases:
// {4 ds_read -> setprio(1) 8 MFMA setprio(0)} | raw barrier | phase 2,
// then lgkm-drain + vmcnt(4) + barrier (WAR protection on rotating buffer).
__global__ __launch_bounds__(THREADS, 2) void gemm_kernel(
    const __bf16* __restrict__ pwb, const float* __restrict__ pb,
    const float* __restrict__ x, const float* __restrict__ leaf,
    float* __restrict__ partial) {
  __shared__ __align__(16) __bf16 Bsm[3][32 * 128];   // 3 x 8 KB
  __shared__ __align__(16) float xsm[NPL][BM];        // [plane][row], 16 KB

  const int tid = threadIdx.x, lane = tid & 63, w = tid >> 6;
  const int lo = lane & 31, half = lane >> 5;

  // XCD-chunked swizzle: 8 mb-sharers of a (nb,s) slice adjacent in one chunk
  const int L = (blockIdx.x & 7) * 128 + (blockIdx.x >> 3);
  const int mb = L & 7;
  const int rest = L >> 3;
  const int nb = rest & 7, s = rest >> 3;
  const int m0 = mb * BM, n0 = nb * BN;
  const int cs = s * NPL;

  // resident leaf fragments: 2 m-subtiles x 32 f32 (this lane's k-half)
  f32x4 lf[2][4][2];
  #pragma unroll
  for (int mt = 0; mt < 2; mt++) {
    const float* lr =
        leaf + (size_t)(m0 + w * 64 + mt * 32 + lo) * NLEAF + half * 8;
    #pragma unroll
    for (int t4 = 0; t4 < 4; t4++) {
      lf[mt][t4][0] = *(const f32x4*)(lr + t4 * 16);
      lf[mt][t4][1] = *(const f32x4*)(lr + t4 * 16 + 4);
    }
  }

  // stage x slice -> f32 [plane][row]
  {
    const float* src = x + (size_t)(m0 + tid) * INF + cs;
    #pragma unroll
    for (int c4 = 0; c4 < NPL / 4; c4++) {
      f32x4 v = *(const f32x4*)(src + c4 * 4);
      #pragma unroll
      for (int j = 0; j < 4; j++) xsm[c4 * 4 + j][tid] = v[j];
    }
  }

  const char* pwc = (const char*)pwb;
  const size_t tbase = (size_t)(nb * 512 + cs) << 13;   // first tile, 8KB each

  auto stage = [&](char* dstb, int t) {
    const char* srcb = pwc + tbase + ((size_t)t << 13);
    #pragma unroll
    for (int j = 0; j < 4; j++)
      gload_lds16(srcb + j * 2048 + tid * 16, dstb + j * 2048 + w * 1024);
  };

  f32x16 acc00 = (f32x16)(0.f), acc01 = (f32x16)(0.f);
  f32x16 acc10 = (f32x16)(0.f), acc11 = (f32x16)(0.f);
  const unsigned swz = (unsigned)(lo & 15) << 4;

  // one half-plane phase: t4 in {2h, 2h+1}: 4 ds_read + 8 MFMA (prio-raised)
  auto do_half = [&](const char* bufc, float xv0, float xv1, int h) {
    bf16x8 bfr[2][2];
    f32x4 p[2][2][2];
    #pragma unroll
    for (int u = 0; u < 2; u++) {
      const int t4 = 2 * h + u;
      const unsigned kb0 = ((unsigned)(t4 * 32 + half * 16)) ^ swz;
      const unsigned kb1 = ((unsigned)(128 + t4 * 32 + half * 16)) ^ swz;
      bfr[u][0] = *(const bf16x8*)(bufc + lo * 256 + kb0);
      bfr[u][1] = *(const bf16x8*)(bufc + lo * 256 + kb1);
      p[u][0][0] = lf[0][t4][0] * xv0; p[u][0][1] = lf[0][t4][1] * xv0;
      p[u][1][0] = lf[1][t4][0] * xv1; p[u][1][1] = lf[1][t4][1] * xv1;
    }
    __builtin_amdgcn_s_setprio(1);
    #pragma unroll
    for (int u = 0; u < 2; u++) {
      bf16x8 a0 = pack8(p[u][0][0], p[u][0][1]);
      bf16x8 a1 = pack8(p[u][1][0], p[u][1][1]);
      acc00 = __builtin_amdgcn_mfma_f32_32x32x16_bf16(a0, bfr[u][0], acc00, 0, 0, 0);
      acc01 = __builtin_amdgcn_mfma_f32_32x32x16_bf16(a0, bfr[u][1], acc01, 0, 0, 0);
      acc10 = __builtin_amdgcn_mfma_f32_32x32x16_bf16(a1, bfr[u][0], acc10, 0, 0, 0);
      acc11 = __builtin_amdgcn_mfma_f32_32x32x16_bf16(a1, bfr[u][1], acc11, 0, 0, 0);
    }
    __builtin_amdgcn_s_setprio(0);
  };

  auto do_step = [&](const char* bufc, int t) {
    const float xv0 = xsm[t][w * 64 + lo];
    const float xv1 = xsm[t][w * 64 + 32 + lo];
    do_half(bufc, xv0, xv1, 0);
    __builtin_amdgcn_s_barrier();          // raw mid-plane barrier (same buf)
    do_half(bufc, xv0, xv1, 1);
  };

  char* bA = (char*)&Bsm[0][0];
  char* bB = (char*)&Bsm[1][0];
  char* bC = (char*)&Bsm[2][0];

  // prologue: stage 0,1; drain stage0 + xsm ds_writes; barrier
  stage(bA, 0);
  stage(bB, 1);
  __builtin_amdgcn_sched_barrier(0);
  asm volatile("s_waitcnt vmcnt(4) lgkmcnt(0)" ::: "memory");
  __builtin_amdgcn_s_barrier();
  __builtin_amdgcn_sched_barrier(0);

  // main loop: counted vmcnt(4) — stage(t+2)'s 4 loads stay in flight;
  // lgkmcnt(0) before the end barrier = WAR fence for the rotating buffer.
  for (int t = 0; t < NPL - 2; ++t) {
    stage(bC, t + 2);
    do_step(bA, t);
    __builtin_amdgcn_sched_barrier(0);
    asm volatile("s_waitcnt vmcnt(4) lgkmcnt(0)" ::: "memory");
    __builtin_amdgcn_s_barrier();
    __builtin_amdgcn_sched_barrier(0);
    char* tmp = bA; bA = bB; bB = bC; bC = tmp;
  }
  do_step(bA, NPL - 2);
  __builtin_amdgcn_sched_barrier(0);
  asm volatile("s_waitcnt vmcnt(0) lgkmcnt(0)" ::: "memory");
  __builtin_amdgcn_s_barrier();
  __builtin_amdgcn_sched_barrier(0);
  do_step(bB, NPL - 1);

  // bias contribution (s == SPLITK-1 only): A = leaf (x==1), W = pb direct
  if (s == SPLITK - 1) {
    #pragma unroll
    for (int t4 = 0; t4 < 4; t4++) {
      bf16x8 a0 = pack8(lf[0][t4][0], lf[0][t4][1]);
      bf16x8 a1 = pack8(lf[1][t4][0], lf[1][t4][1]);
      #pragma unroll
      for (int nt = 0; nt < 2; nt++) {
        const float* pr =
            pb + (size_t)(n0 + nt * 32 + lo) * NLEAF + t4 * 16 + half * 8;
        f32x4 c0 = *(const f32x4*)pr, c1 = *(const f32x4*)(pr + 4);
        bf16x8 bb = pack8(c0, c1);
        if (nt == 0) {
          acc00 = __builtin_amdgcn_mfma_f32_32x32x16_bf16(a0, bb, acc00, 0, 0, 0);
          acc10 = __builtin_amdgcn_mfma_f32_32x32x16_bf16(a1, bb, acc10, 0, 0, 0);
        } else {
          acc01 = __builtin_amdgcn_mfma_f32_32x32x16_bf16(a0, bb, acc01, 0, 0, 0);
          acc11 = __builtin_amdgcn_mfma_f32_32x32x16_bf16(a1, bb, acc11, 0, 0, 0);
        }
      }
    }
  }

  // epilogue: partial[s]; D row = (e&3)+8*(e>>2)+4*half, col = lo
  #pragma unroll
  for (int mt = 0; mt < 2; mt++) {
    float* dst =
        partial + ((size_t)s * BATCH + m0 + w * 64 + mt * 32) * OUTF + n0;
    #pragma unroll
    for (int e = 0; e < 16; e++) {
      int row = (e & 3) + 8 * (e >> 2) + 4 * half;
      if (mt == 0) {
        dst[(size_t)row * OUTF + lo] = acc00[e];
        dst[(size_t)row * OUTF + 32 + lo] = acc01[e];
      } else {
        dst[(size_t)row * OUTF + lo] = acc10[e];
        dst[(size_t)row * OUTF + 32 + lo] = acc11[e];
      }
    }
  }
}

// ---------------- kernel 3: split-K reduce ----------------
__global__ __launch_bounds__(256) void reduce_kernel(
    const float* __restrict__ partial, float* __restrict__ out) {
  size_t e = ((size_t)blockIdx.x * 256 + threadIdx.x) * 4;
  f32x4 sum = (f32x4){0.f, 0.f, 0.f, 0.f};
  #pragma unroll
  for (int s = 0; s < SPLITK; s++)
    sum += *(const f32x4*)(partial + (size_t)s * BATCH * OUTF + e);
  *(f32x4*)(out + e) = sum;
}

extern "C" void kernel_launch(void* const* d_in, const int* in_sizes, int n_in,
                              void* d_out, int out_size, void* d_ws, size_t ws_size,
                              hipStream_t stream) {
  const float* x  = (const float*)d_in[0];
  const float* gw = (const float*)d_in[1];
  const float* gb = (const float*)d_in[2];
  const float* pw = (const float*)d_in[3];
  const float* pb = (const float*)d_in[4];
  float* out = (float*)d_out;

  float*  leaf    = (float*)d_ws;                          // 256 KB
  __bf16* pwb     = (__bf16*)((char*)d_ws + (1 << 20));    // 32 MB
  float*  partial = (float*)((char*)d_ws + (33ull << 20)); // 32 MB

  prep_kernel<<<256 + 8192, 256, 0, stream>>>(x, gw, gb, pw, leaf, pwb);
  gemm_kernel<<<8 * 8 * SPLITK, THREADS, 0, stream>>>(pwb, pb, x, leaf, partial);
  reduce_kernel<<<(BATCH * OUTF) / (256 * 4), 256, 0, stream>>>(partial, out);
}

// Round 14
// 75.679 us; speedup vs baseline: 2.3826x; 1.0141x over previous
//
#include <hip/hip_runtime.h>
#include <hip/hip_bf16.h>

#define TDEPTH 6
#define NLEAF 64
#define NGATE 63
#define INF 512
#define OUTF 512
#define BATCH 1024

#define BM 128
#define BN 32
#define SPLITK 16
#define THREADS 128
#define NPL 32        // planes per block (512/SPLITK)

typedef __attribute__((ext_vector_type(4)))  float f32x4;
typedef __attribute__((ext_vector_type(16))) float f32x16;
typedef __attribute__((ext_vector_type(8)))  __bf16 bf16x8;

__device__ __forceinline__ bf16x8 pack8(f32x4 a, f32x4 b) {
  bf16x8 w;
  w[0] = (__bf16)a[0]; w[1] = (__bf16)a[1];
  w[2] = (__bf16)a[2]; w[3] = (__bf16)a[3];
  w[4] = (__bf16)b[0]; w[5] = (__bf16)b[1];
  w[6] = (__bf16)b[2]; w[7] = (__bf16)b[3];
  return w;
}

// ---------------- kernel 1: leaf probs + pwb pack ----------------
// blocks [0,256): leaf.  blocks [256, 256+8208): pack pw (+pb as plane 512)
// into 4KB tiles per (nb32, i): [32 o-rows][8 granules]; granule at pos p of
// row r holds k-granule g = p ^ (r&7)  (bakes the 128B-row XOR swizzle).
// Gemm stages tiles LINEARLY, reads byte r*128 + ((kbyte) ^ ((r&7)<<4)).
__global__ __launch_bounds__(256) void prep_kernel(
    const float* __restrict__ x, const float* __restrict__ gw,
    const float* __restrict__ gb, const float* __restrict__ pw,
    const float* __restrict__ pb, float* __restrict__ leaf,
    __bf16* __restrict__ pwb) {
  const int tid = threadIdx.x;
  if (blockIdx.x < 256) {
    const int wid = tid >> 6, lane = tid & 63;
    const int b = blockIdx.x * 4 + wid;
    __shared__ float g[4][NLEAF];
    if (lane < NGATE) {
      const float* xr = x + (size_t)b * INF;
      float a0 = 0.f, a1 = 0.f, a2 = 0.f, a3 = 0.f;
      #pragma unroll 4
      for (int i = 0; i < INF; i += 4) {
        a0 += xr[i + 0] * gw[(i + 0) * NGATE + lane];
        a1 += xr[i + 1] * gw[(i + 1) * NGATE + lane];
        a2 += xr[i + 2] * gw[(i + 2) * NGATE + lane];
        a3 += xr[i + 3] * gw[(i + 3) * NGATE + lane];
      }
      float t = (a0 + a1) + (a2 + a3) + gb[lane];
      g[wid][lane] = 1.0f / (1.0f + __expf(-t));
    }
    __syncthreads();
    float p = 1.0f;
    #pragma unroll
    for (int d = 0; d < TDEPTH; d++) {
      int prefix = lane >> (TDEPTH - 1 - d);
      int node = (1 << d) - 1 + (prefix >> 1);
      float gv = g[wid][node];
      p *= (prefix & 1) ? (1.0f - gv) : gv;
    }
    leaf[(size_t)b * NLEAF + lane] = p;
  } else {
    const unsigned Q = (blockIdx.x - 256) * 256 + tid;   // granule id
    const unsigned tile = Q >> 8;            // nb32*513 + i
    const unsigned nb32 = tile / 513;
    const unsigned i = tile - nb32 * 513;
    const unsigned q = Q & 255;
    const unsigned r = q >> 3;               // o-row 0..31
    const unsigned g = (q & 7) ^ (r & 7);    // k-granule
    const unsigned o = nb32 * 32 + r;
    const float* src = (i < INF) ? (pw + ((size_t)o * INF + i) * NLEAF + g * 8)
                                 : (pb + (size_t)o * NLEAF + g * 8);
    f32x4 a = *(const f32x4*)src, b = *(const f32x4*)(src + 4);
    *(bf16x8*)((char*)pwb + (size_t)Q * 16) = pack8(a, b);
  }
}

// async 16B global -> LDS (wave-uniform LDS base; +lane*16 implicit)
__device__ __forceinline__ void gload_lds16(const void* g, void* l) {
  __builtin_amdgcn_global_load_lds(
      (const __attribute__((address_space(1))) void*)g,
      (__attribute__((address_space(3))) void*)l, 16, 0, 0);
}

// ---------------- kernel 2: fused GEMM (swapped operands) ----------------
// D_i[o,b] = sum_l pw[o,i,l]*leaf[b,l]  via mfma(A=pw from LDS, B=leaf regs)
// acc[o,b] += x[b,i] * D_i   (x-scale = one scalar per lane: 32 v_fmac/plane)
// 2 waves (128 thr), per-wave tile 32o x 64b; 3 x 4KB B-buffers, counted
// vmcnt(2); 20 KB LDS -> 8 blocks/CU; VGPR<=128 -> 4 waves/SIMD.
__global__ __launch_bounds__(THREADS, 4) void gemm_kernel(
    const __bf16* __restrict__ pwb, const float* __restrict__ x,
    const float* __restrict__ leaf, float* __restrict__ partial) {
  __shared__ __align__(16) __bf16 Bsm[3][2048];   // 3 x 4 KB pw tiles
  __shared__ __align__(16) __bf16 xsm[NPL][BM];   // [plane][b-row], 8 KB

  const int tid = threadIdx.x, lane = tid & 63, w = tid >> 6;
  const int lo = lane & 31, half = lane >> 5;

  // XCD-chunked swizzle: 2048 blocks -> 8 chunks of 256
  const int L = ((int)blockIdx.x & 7) * 256 + ((int)blockIdx.x >> 3);
  const int mb = L & 7;
  const int rest = L >> 3;
  const int nb = rest & 15, s = rest >> 4;
  const int m0 = mb * BM, o0 = nb * BN;
  const int cs = s * NPL;
  const int count = NPL + (s == SPLITK - 1 ? 1 : 0);  // +1 = bias plane 512

  // resident leaf fragments (bf16): lane lo = b-col, elems = l-range
  bf16x8 lfb[2][4];
  #pragma unroll
  for (int mt = 0; mt < 2; mt++) {
    const float* lr =
        leaf + (size_t)(m0 + w * 64 + mt * 32 + lo) * NLEAF + half * 8;
    #pragma unroll
    for (int t4 = 0; t4 < 4; t4++)
      lfb[mt][t4] = pack8(*(const f32x4*)(lr + t4 * 16),
                          *(const f32x4*)(lr + t4 * 16 + 4));
  }

  // stage x slice -> bf16 [plane][row]
  {
    const float* src = x + (size_t)(m0 + tid) * INF + cs;
    #pragma unroll
    for (int c4 = 0; c4 < NPL / 4; c4++) {
      f32x4 v = *(const f32x4*)(src + c4 * 4);
      #pragma unroll
      for (int j = 0; j < 4; j++) xsm[c4 * 4 + j][tid] = (__bf16)v[j];
    }
  }

  const char* tb = (const char*)pwb + ((size_t)(nb * 513 + cs) << 12);

  auto stage = [&](char* dstb, int t) {
    const char* srcb = tb + ((size_t)t << 12);
    #pragma unroll
    for (int rnd = 0; rnd < 2; rnd++)
      gload_lds16(srcb + rnd * 2048 + tid * 16, dstb + rnd * 2048 + w * 1024);
  };

  f32x16 acc0 = (f32x16)(0.f), acc1 = (f32x16)(0.f);
  const unsigned swz = (unsigned)(lo & 7) << 4;

  auto do_step = [&](const char* bufc, int t) {
    float xv0 = 1.0f, xv1 = 1.0f;
    if (t < NPL) {
      xv0 = (float)xsm[t][w * 64 + lo];
      xv1 = (float)xsm[t][w * 64 + 32 + lo];
    }
    bf16x8 af[4];
    #pragma unroll
    for (int t4 = 0; t4 < 4; t4++)
      af[t4] = *(const bf16x8*)(bufc + lo * 128 +
                                (((unsigned)(t4 * 32 + half * 16)) ^ swz));
    {
      f32x16 D = (f32x16)(0.f);
      #pragma unroll
      for (int t4 = 0; t4 < 4; t4++)
        D = __builtin_amdgcn_mfma_f32_32x32x16_bf16(af[t4], lfb[0][t4], D, 0, 0, 0);
      acc0 += D * xv0;
    }
    {
      f32x16 D = (f32x16)(0.f);
      #pragma unroll
      for (int t4 = 0; t4 < 4; t4++)
        D = __builtin_amdgcn_mfma_f32_32x32x16_bf16(af[t4], lfb[1][t4], D, 0, 0, 0);
      acc1 += D * xv1;
    }
  };

  char* bA = (char*)&Bsm[0][0];
  char* bB = (char*)&Bsm[1][0];
  char* bC = (char*)&Bsm[2][0];

  // prologue: stage 0,1; drain stage0 + xsm ds_writes; barrier
  stage(bA, 0);
  stage(bB, 1);
  __builtin_amdgcn_sched_barrier(0);
  asm volatile("s_waitcnt vmcnt(2) lgkmcnt(0)" ::: "memory");
  __builtin_amdgcn_s_barrier();
  __builtin_amdgcn_sched_barrier(0);

  // main loop: counted vmcnt(2) — stage(t+2)'s 2 loads stay in flight;
  // lgkmcnt(0) = WAR fence (this iter's ds_reads) for the rotating buffer.
  for (int t = 0; t < count - 2; ++t) {
    stage(bC, t + 2);
    do_step(bA, t);
    __builtin_amdgcn_sched_barrier(0);
    asm volatile("s_waitcnt vmcnt(2) lgkmcnt(0)" ::: "memory");
    __builtin_amdgcn_s_barrier();
    __builtin_amdgcn_sched_barrier(0);
    char* tmp = bA; bA = bB; bB = bC; bC = tmp;
  }
  do_step(bA, count - 2);
  __builtin_amdgcn_sched_barrier(0);
  asm volatile("s_waitcnt vmcnt(0) lgkmcnt(0)" ::: "memory");
  __builtin_amdgcn_s_barrier();
  __builtin_amdgcn_sched_barrier(0);
  do_step(bB, count - 1);

  // epilogue: partial layout [s][o][b] (TRANSPOSED) — coalesced over b=lo
  #pragma unroll
  for (int mt = 0; mt < 2; mt++) {
    float* dstb = partial + ((size_t)s * OUTF + o0) * BATCH +
                  (m0 + w * 64 + mt * 32);
    const f32x16 a = mt ? acc1 : acc0;
    #pragma unroll
    for (int e = 0; e < 16; e++) {
      int row = (e & 3) + 8 * (e >> 2) + 4 * half;   // o within tile
      dstb[(size_t)row * BATCH + lo] = a[e];
    }
  }
}

// ---------------- kernel 3: split-K reduce + transpose ----------------
// partial[s][o][b] -> out[b][o]
__global__ __launch_bounds__(256) void reduce_kernel(
    const float* __restrict__ partial, float* __restrict__ out) {
  __shared__ float tile[32][65];
  const int t = threadIdx.x;
  const int O0 = ((int)blockIdx.x >> 4) * 32;
  const int B0 = ((int)blockIdx.x & 15) * 64;
  #pragma unroll
  for (int rep = 0; rep < 8; rep++) {
    const int idx = rep * 256 + t;
    const int o = idx >> 6, b = idx & 63;
    float sum = 0.f;
    #pragma unroll
    for (int s = 0; s < SPLITK; s++)
      sum += partial[((size_t)s * OUTF + O0 + o) * BATCH + B0 + b];
    tile[o][b] = sum;
  }
  __syncthreads();
  #pragma unroll
  for (int rep = 0; rep < 8; rep++) {
    const int idx = rep * 256 + t;
    const int b = idx >> 5, o = idx & 31;
    out[(size_t)(B0 + b) * OUTF + O0 + o] = tile[o][b];
  }
}

extern "C" void kernel_launch(void* const* d_in, const int* in_sizes, int n_in,
                              void* d_out, int out_size, void* d_ws, size_t ws_size,
                              hipStream_t stream) {
  const float* x  = (const float*)d_in[0];
  const float* gw = (const float*)d_in[1];
  const float* gb = (const float*)d_in[2];
  const float* pw = (const float*)d_in[3];
  const float* pb = (const float*)d_in[4];
  float* out = (float*)d_out;

  float*  leaf    = (float*)d_ws;                            // 256 KB
  __bf16* pwb     = (__bf16*)((char*)d_ws + (256 << 10));    // 33.6 MB
  float*  partial = (float*)((char*)d_ws + (256 << 10) + (size_t)16 * 513 * 4096);

  prep_kernel<<<256 + 8208, 256, 0, stream>>>(x, gw, gb, pw, pb, leaf, pwb);
  gemm_kernel<<<8 * 16 * SPLITK, THREADS, 0, stream>>>(pwb, x, leaf, partial);
  reduce_kernel<<<256, 256, 0, stream>>>(partial, out);
}